// Round 2
// baseline (11965.839 us; speedup 1.0000x reference)
//
#include <hip/hip_runtime.h>
#include <hip/hip_bf16.h>
#include <stdint.h>

#define TB 32      // batch
#define TT 1024    // time steps
#define TN 512     // hidden

typedef __attribute__((ext_vector_type(8))) short short8;
typedef __attribute__((ext_vector_type(4))) float f32x4;
typedef __attribute__((ext_vector_type(4))) short short4v;

static __device__ inline unsigned short f2bf(float f) {
  union { __hip_bfloat16 h; unsigned short u; } c;
  c.h = __float2bfloat16(f);
  return c.u;
}

static __device__ inline short8 pack_bf8(const float* __restrict__ p) {
  float4 a = *(const float4*)p;
  float4 b = *(const float4*)(p + 4);
  short8 o;
  o[0] = (short)f2bf(a.x); o[1] = (short)f2bf(a.y);
  o[2] = (short)f2bf(a.z); o[3] = (short)f2bf(a.w);
  o[4] = (short)f2bf(b.x); o[5] = (short)f2bf(b.y);
  o[6] = (short)f2bf(b.z); o[7] = (short)f2bf(b.w);
  return o;
}

// ---------------- prep: zero h ping-pong buffers & barrier words (ws is 0xAA-poisoned) ----
__global__ void prep_kernel(short4v* __restrict__ hbuf, unsigned* __restrict__ bars) {
  const int i = blockIdx.x * 256 + threadIdx.x;
  if (i < (2 * 2 * TB * TN / 4)) {  // 16384 short4v
    short4v z; z.x = 0; z.y = 0; z.z = 0; z.w = 0;
    hbuf[i] = z;
  }
  if (i < 64) bars[i] = 0u;
}

// ---------------- persistent bidirectional GRU recurrence ----------------
// grid: 32 blocks (dir = blk>>4, slice j = blk&15), 256 threads (4 waves).
// wave w: mt = w&1 (batch rows mt*16..+15), nt = w>>1 (cols nt*16..+15 of slice).
__global__ __launch_bounds__(256, 1) void gru_kernel(
    const float* __restrict__ x,            // [B][T][N] fp32
    const float* __restrict__ wihF, const float* __restrict__ whhF,
    const float* __restrict__ wihB, const float* __restrict__ whhB,
    const float* __restrict__ bihF, const float* __restrict__ bhhF,
    const float* __restrict__ bihB, const float* __restrict__ bhhB,
    unsigned short* __restrict__ hbuf,      // [2 dirs][2 bufs][B][N] bf16
    unsigned* __restrict__ bars,            // [2 dirs], 128B apart
    float* __restrict__ out)                // [B][T][2N] fp32
{
  const int wg   = blockIdx.x;
  const int dir  = wg >> 4;
  const int j    = wg & 15;
  const int tid  = threadIdx.x;
  const int lane = tid & 63;
  const int w    = tid >> 6;
  const int mt   = w & 1;
  const int nt   = w >> 1;
  const int l15  = lane & 15;
  const int l4   = lane >> 4;                 // 0..3
  const int coln = j * 32 + nt * 16 + l15;    // global hidden col 0..511
  const int brow = mt * 16 + l15;             // batch row for A-frags

  const float* wih = dir ? wihB : wihF;
  const float* whh = dir ? whhB : whhF;
  const float* bih = dir ? bihB : bihF;
  const float* bhh = dir ? bhhB : bhhF;
  unsigned short* hb = hbuf + dir * (2 * TB * TN);
  unsigned* bar = bars + dir * 32;

  // Wih r,z gate fragments in LDS, fragment-ordered (conflict-free ds_read_b128). 64KB.
  __shared__ unsigned short wih_lds[2][2][16][512];

  // ---- one-time: convert weights fp32 -> bf16 fragments ----
  // Whh (all 3 gates) + Wih n-gate persistent in VGPRs.
  short8 bwhh[3][16];
#pragma unroll
  for (int g = 0; g < 3; ++g)
#pragma unroll
    for (int ks = 0; ks < 16; ++ks)
      bwhh[g][ks] = pack_bf8(whh + (size_t)(g * TN + coln) * TN + ks * 32 + l4 * 8);

  short8 bwih_n[16];
#pragma unroll
  for (int ks = 0; ks < 16; ++ks)
    bwih_n[ks] = pack_bf8(wih + (size_t)(2 * TN + coln) * TN + ks * 32 + l4 * 8);

  // Wih r,z -> LDS (written by mt==0 waves, read by all waves of same nt).
  if (mt == 0) {
#pragma unroll
    for (int g = 0; g < 2; ++g)
#pragma unroll
      for (int ks = 0; ks < 16; ++ks) {
        short8 f = pack_bf8(wih + (size_t)(g * TN + coln) * TN + ks * 32 + l4 * 8);
        *(short8*)&wih_lds[nt][g][ks][lane * 8] = f;
      }
  }

  const float bias_r  = bih[coln] + bhh[coln];
  const float bias_z  = bih[TN + coln] + bhh[TN + coln];
  const float bias_in = bih[2 * TN + coln];
  const float bias_hn = bhh[2 * TN + coln];

  // fp32 recurrent state for this wave's own 4 (row,col) patch entries.
  float hstate[4] = {0.f, 0.f, 0.f, 0.f};
  int dead = 0;  // set if barrier wait ever times out (prevents GPU hang)

  __syncthreads();  // wih_lds ready

  for (int t = 0; t < TT; ++t) {
    const int st = dir ? (TT - 1 - t) : t;   // source time index into x

    f32x4 acc_r  = {bias_r,  bias_r,  bias_r,  bias_r};
    f32x4 acc_z  = {bias_z,  bias_z,  bias_z,  bias_z};
    f32x4 acc_in = {bias_in, bias_in, bias_in, bias_in};
    f32x4 acc_hn = {bias_hn, bias_hn, bias_hn, bias_hn};

    // ---- gi = x_t @ Wih^T (barrier-independent: overlaps the wait) ----
    const float* xr = x + (size_t)brow * (TT * TN) + (size_t)st * TN + l4 * 8;
    short8 af[16];
#pragma unroll
    for (int ks = 0; ks < 16; ++ks) af[ks] = pack_bf8(xr + ks * 32);
#pragma unroll
    for (int ks = 0; ks < 16; ++ks) {
      short8 b0 = *(const short8*)&wih_lds[nt][0][ks][lane * 8];
      acc_r = __builtin_amdgcn_mfma_f32_16x16x32_bf16(af[ks], b0, acc_r, 0, 0, 0);
      short8 b1 = *(const short8*)&wih_lds[nt][1][ks][lane * 8];
      acc_z = __builtin_amdgcn_mfma_f32_16x16x32_bf16(af[ks], b1, acc_z, 0, 0, 0);
      acc_in = __builtin_amdgcn_mfma_f32_16x16x32_bf16(af[ks], bwih_n[ks], acc_in, 0, 0, 0);
    }

    // x patch for the output epilogue (fp32, barrier-independent)
    const int bpat = mt * 16 + l4 * 4;
    float xv[4];
#pragma unroll
    for (int r = 0; r < 4; ++r)
      xv[r] = x[(size_t)(bpat + r) * (TT * TN) + (size_t)st * TN + coln];

    // ---- wait for all 64 waves of this direction to finish step t-1 ----
    if (t > 0) {
      if (lane == 0 && !dead) {
        const unsigned target = 64u * (unsigned)t;
        int spins = 0;
        while (__hip_atomic_load(bar, __ATOMIC_RELAXED, __HIP_MEMORY_SCOPE_AGENT) < target) {
          __builtin_amdgcn_s_sleep(2);
          if (++spins > (1 << 22)) { dead = 1; break; }
        }
      }
      __builtin_amdgcn_fence(__ATOMIC_ACQUIRE, "agent");
    }

    // ---- gh = h_{t-1} @ Whh^T ----
    const unsigned short* hr = hb + ((t + 1) & 1) * (TB * TN) + (size_t)brow * TN + l4 * 8;
#pragma unroll
    for (int ks = 0; ks < 16; ++ks) af[ks] = *(const short8*)(hr + ks * 32);
#pragma unroll
    for (int ks = 0; ks < 16; ++ks) {
      acc_r  = __builtin_amdgcn_mfma_f32_16x16x32_bf16(af[ks], bwhh[0][ks], acc_r, 0, 0, 0);
      acc_z  = __builtin_amdgcn_mfma_f32_16x16x32_bf16(af[ks], bwhh[1][ks], acc_z, 0, 0, 0);
      acc_hn = __builtin_amdgcn_mfma_f32_16x16x32_bf16(af[ks], bwhh[2][ks], acc_hn, 0, 0, 0);
    }

    // ---- gates + state update + stores ----
    unsigned short* hw = hb + (t & 1) * (TB * TN);
#pragma unroll
    for (int r = 0; r < 4; ++r) {
      float rg = 1.0f / (1.0f + __expf(-acc_r[r]));
      float zg = 1.0f / (1.0f + __expf(-acc_z[r]));
      float e2 = __expf(2.0f * (acc_in[r] + rg * acc_hn[r]));
      float ng = 1.0f - 2.0f / (e2 + 1.0f);
      float hnew = (1.0f - zg) * ng + zg * hstate[r];
      hstate[r] = hnew;
      const int b = bpat + r;
      __builtin_nontemporal_store(f2bf(hnew), hw + (size_t)b * TN + coln);
      __builtin_nontemporal_store(hnew + xv[r],
          out + (size_t)b * (TT * 2 * TN) + (size_t)t * (2 * TN) + dir * TN + coln);
    }

    // ---- publish step t ----
    __builtin_amdgcn_fence(__ATOMIC_RELEASE, "agent");
    if (lane == 0)
      __hip_atomic_fetch_add(bar, 1u, __ATOMIC_RELAXED, __HIP_MEMORY_SCOPE_AGENT);
  }
}

// ---------------- launch ----------------
extern "C" void kernel_launch(void* const* d_in, const int* in_sizes, int n_in,
                              void* d_out, int out_size, void* d_ws, size_t ws_size,
                              hipStream_t stream) {
  const float* x    = (const float*)d_in[0];
  const float* WihF = (const float*)d_in[1];
  const float* WhhF = (const float*)d_in[2];
  const float* bihF = (const float*)d_in[3];
  const float* bhhF = (const float*)d_in[4];
  const float* WihB = (const float*)d_in[5];
  const float* WhhB = (const float*)d_in[6];
  const float* bihB = (const float*)d_in[7];
  const float* bhhB = (const float*)d_in[8];

  // ws layout: hbuf (2 dirs * 2 bufs * 32 * 512 bf16 = 131072 B) + bars (256 B)
  unsigned short* hbuf = (unsigned short*)d_ws;
  unsigned* bars       = (unsigned*)((char*)d_ws + (size_t)2 * 2 * TB * TN * 2);

  prep_kernel<<<64, 256, 0, stream>>>((short4v*)hbuf, bars);

  gru_kernel<<<32, 256, 0, stream>>>(
      x, WihF, WhhF, WihB, WhhB,
      bihF, bhhF, bihB, bhhB,
      hbuf, bars, (float*)d_out);
}

// Round 3
// 9265.493 us; speedup vs baseline: 1.2914x; 1.2914x over previous
//
#include <hip/hip_runtime.h>
#include <hip/hip_bf16.h>
#include <stdint.h>

#define TB 32      // batch
#define TT 1024    // time steps
#define TN 512     // hidden

typedef __attribute__((ext_vector_type(8))) short short8;
typedef __attribute__((ext_vector_type(4))) float f32x4;
typedef __attribute__((ext_vector_type(4))) short short4v;

static __device__ inline unsigned short f2bf(float f) {
  union { __hip_bfloat16 h; unsigned short u; } c;
  c.h = __float2bfloat16(f);
  return c.u;
}

static __device__ inline short8 pack_bf8(const float* __restrict__ p) {
  float4 a = *(const float4*)p;
  float4 b = *(const float4*)(p + 4);
  short8 o;
  o[0] = (short)f2bf(a.x); o[1] = (short)f2bf(a.y);
  o[2] = (short)f2bf(a.z); o[3] = (short)f2bf(a.w);
  o[4] = (short)f2bf(b.x); o[5] = (short)f2bf(b.y);
  o[6] = (short)f2bf(b.z); o[7] = (short)f2bf(b.w);
  return o;
}

// ---------------- prep: zero h ping-pong buffers & barrier words (ws is 0xAA-poisoned) ----
__global__ void prep_kernel(short4v* __restrict__ hbuf, unsigned* __restrict__ bars) {
  const int i = blockIdx.x * 256 + threadIdx.x;
  if (i < (2 * 2 * TB * TN / 4)) {  // 16384 short4v
    short4v z; z.x = 0; z.y = 0; z.z = 0; z.w = 0;
    hbuf[i] = z;
  }
  if (i < 128) bars[i] = 0u;
}

// ---------------- persistent bidirectional GRU recurrence ----------------
// grid: 32 blocks (dir = blk>>4, slice j = blk&15), 256 threads (4 waves).
// wave w: mt = w&1 (batch rows mt*16..+15), nt = w>>1 (cols nt*16..+15 of slice).
// Cross-WG h exchange via relaxed agent-scope atomics (per-access coherent, sc0/sc1)
// -- NO agent fences (buffer_wbl2/buffer_inv full-L2 walks killed round-2 perf).
// Barrier is split per (dir, mt): wave mt only consumes h rows produced by same-mt waves.
__global__ __launch_bounds__(256, 1) void gru_kernel(
    const float* __restrict__ x,            // [B][T][N] fp32
    const float* __restrict__ wihF, const float* __restrict__ whhF,
    const float* __restrict__ wihB, const float* __restrict__ whhB,
    const float* __restrict__ bihF, const float* __restrict__ bhhF,
    const float* __restrict__ bihB, const float* __restrict__ bhhB,
    unsigned short* __restrict__ hbuf,      // [2 dirs][2 bufs][B][N] bf16
    unsigned* __restrict__ bars,            // [2 dirs][2 mt], 128B apart
    float* __restrict__ out)                // [B][T][2N] fp32
{
  const int wg   = blockIdx.x;
  const int dir  = wg >> 4;
  const int j    = wg & 15;
  const int tid  = threadIdx.x;
  const int lane = tid & 63;
  const int w    = tid >> 6;
  const int mt   = w & 1;
  const int nt   = w >> 1;
  const int l15  = lane & 15;
  const int l4   = lane >> 4;                 // 0..3
  const int coln = j * 32 + nt * 16 + l15;    // global hidden col 0..511
  const int brow = mt * 16 + l15;             // batch row for A-frags

  const float* wih = dir ? wihB : wihF;
  const float* whh = dir ? whhB : whhF;
  const float* bih = dir ? bihB : bihF;
  const float* bhh = dir ? bhhB : bhhF;
  unsigned short* hb = hbuf + dir * (2 * TB * TN);
  unsigned* bar = bars + (dir * 2 + mt) * 32;   // 128B-separated counters

  // Wih r,z gate fragments in LDS, fragment-ordered (conflict-free ds_read_b128). 64KB.
  __shared__ unsigned short wih_lds[2][2][16][512];

  // ---- one-time: convert weights fp32 -> bf16 fragments ----
  short8 bwhh[3][16];
#pragma unroll
  for (int g = 0; g < 3; ++g)
#pragma unroll
    for (int ks = 0; ks < 16; ++ks)
      bwhh[g][ks] = pack_bf8(whh + (size_t)(g * TN + coln) * TN + ks * 32 + l4 * 8);

  short8 bwih_n[16];
#pragma unroll
  for (int ks = 0; ks < 16; ++ks)
    bwih_n[ks] = pack_bf8(wih + (size_t)(2 * TN + coln) * TN + ks * 32 + l4 * 8);

  if (mt == 0) {
#pragma unroll
    for (int g = 0; g < 2; ++g)
#pragma unroll
      for (int ks = 0; ks < 16; ++ks) {
        short8 f = pack_bf8(wih + (size_t)(g * TN + coln) * TN + ks * 32 + l4 * 8);
        *(short8*)&wih_lds[nt][g][ks][lane * 8] = f;
      }
  }

  const float bias_r  = bih[coln] + bhh[coln];
  const float bias_z  = bih[TN + coln] + bhh[TN + coln];
  const float bias_in = bih[2 * TN + coln];
  const float bias_hn = bhh[2 * TN + coln];

  // fp32 recurrent state for this wave's own 4 (row,col) patch entries.
  float hstate[4] = {0.f, 0.f, 0.f, 0.f};
  int dead = 0;  // set if barrier wait ever times out (prevents container-killing hang)

  __syncthreads();  // wih_lds ready

  const int bpat = mt * 16 + l4 * 4;

  for (int t = 0; t < TT; ++t) {
    const int st = dir ? (TT - 1 - t) : t;   // source time index into x

    f32x4 acc_r  = {bias_r,  bias_r,  bias_r,  bias_r};
    f32x4 acc_z  = {bias_z,  bias_z,  bias_z,  bias_z};
    f32x4 acc_in = {bias_in, bias_in, bias_in, bias_in};
    f32x4 acc_hn = {bias_hn, bias_hn, bias_hn, bias_hn};

    // ---- gi = x_t @ Wih^T (barrier-independent: overlaps the wait) ----
    const float* xr = x + (size_t)brow * (TT * TN) + (size_t)st * TN + l4 * 8;
    short8 af[16];
#pragma unroll
    for (int ks = 0; ks < 16; ++ks) af[ks] = pack_bf8(xr + ks * 32);
#pragma unroll
    for (int ks = 0; ks < 16; ++ks) {
      short8 b0 = *(const short8*)&wih_lds[nt][0][ks][lane * 8];
      acc_r = __builtin_amdgcn_mfma_f32_16x16x32_bf16(af[ks], b0, acc_r, 0, 0, 0);
      short8 b1 = *(const short8*)&wih_lds[nt][1][ks][lane * 8];
      acc_z = __builtin_amdgcn_mfma_f32_16x16x32_bf16(af[ks], b1, acc_z, 0, 0, 0);
      acc_in = __builtin_amdgcn_mfma_f32_16x16x32_bf16(af[ks], bwih_n[ks], acc_in, 0, 0, 0);
    }

    // x patch for the output epilogue (fp32, barrier-independent)
    float xv[4];
#pragma unroll
    for (int r = 0; r < 4; ++r)
      xv[r] = x[(size_t)(bpat + r) * (TT * TN) + (size_t)st * TN + coln];

    // ---- wait: all 32 same-mt waves of this direction finished step t-1 ----
    if (t > 0) {
      if (lane == 0 && !dead) {
        const unsigned target = 32u * (unsigned)t;
        int spins = 0;
        while (__hip_atomic_load(bar, __ATOMIC_RELAXED, __HIP_MEMORY_SCOPE_AGENT) < target) {
          if (++spins > (1 << 24)) { dead = 1; break; }
        }
      }
      asm volatile("" ::: "memory");  // compiler barrier: keep h loads below the poll
    }

    // ---- gh = h_{t-1} @ Whh^T  (coherent 8B loads: bypass stale L1/L2, hit IF$) ----
    const unsigned short* hr = hb + ((t + 1) & 1) * (TB * TN) + (size_t)brow * TN + l4 * 8;
#pragma unroll
    for (int ks = 0; ks < 16; ++ks) {
      union { unsigned long long u[2]; short8 s; } cvt;
      cvt.u[0] = __hip_atomic_load((const unsigned long long*)(hr + ks * 32),
                                   __ATOMIC_RELAXED, __HIP_MEMORY_SCOPE_AGENT);
      cvt.u[1] = __hip_atomic_load((const unsigned long long*)(hr + ks * 32 + 4),
                                   __ATOMIC_RELAXED, __HIP_MEMORY_SCOPE_AGENT);
      af[ks] = cvt.s;
    }
#pragma unroll
    for (int ks = 0; ks < 16; ++ks) {
      acc_r  = __builtin_amdgcn_mfma_f32_16x16x32_bf16(af[ks], bwhh[0][ks], acc_r, 0, 0, 0);
      acc_z  = __builtin_amdgcn_mfma_f32_16x16x32_bf16(af[ks], bwhh[1][ks], acc_z, 0, 0, 0);
      acc_hn = __builtin_amdgcn_mfma_f32_16x16x32_bf16(af[ks], bwhh[2][ks], acc_hn, 0, 0, 0);
    }

    // ---- gates + state update; publish h ASAP (coherent packed 4B stores) ----
    unsigned short* hw = hb + (t & 1) * (TB * TN);
    float hout[4];
#pragma unroll
    for (int r = 0; r < 4; ++r) {
      float rg = 1.0f / (1.0f + __expf(-acc_r[r]));
      float zg = 1.0f / (1.0f + __expf(-acc_z[r]));
      float e2 = __expf(2.0f * (acc_in[r] + rg * acc_hn[r]));
      float ng = 1.0f - 2.0f / (e2 + 1.0f);
      float hnew = (1.0f - zg) * ng + zg * hstate[r];
      hstate[r] = hnew;
      hout[r] = hnew;
      // pack (col, col+1) from the even/odd lane pair into one 4B coherent store
      unsigned short us = f2bf(hnew);
      int other = __shfl_xor((int)us, 1, 64);
      if ((lane & 1) == 0) {
        unsigned val = (unsigned)us | ((unsigned)(other & 0xFFFF) << 16);
        __hip_atomic_store((unsigned*)(hw + (size_t)(bpat + r) * TN + coln), val,
                           __ATOMIC_RELAXED, __HIP_MEMORY_SCOPE_AGENT);
      }
    }

    // ---- publish step t: drain h stores, then bump the (dir,mt) counter ----
    __builtin_amdgcn_s_waitcnt(0);
    if (lane == 0)
      (void)__hip_atomic_fetch_add(bar, 1u, __ATOMIC_RELAXED, __HIP_MEMORY_SCOPE_AGENT);

    // ---- out stores AFTER the publish (drain during next step's overlap window) ----
#pragma unroll
    for (int r = 0; r < 4; ++r) {
      __builtin_nontemporal_store(hout[r] + xv[r],
          out + (size_t)(bpat + r) * (TT * 2 * TN) + (size_t)t * (2 * TN) + dir * TN + coln);
    }
  }
}

// ---------------- launch ----------------
extern "C" void kernel_launch(void* const* d_in, const int* in_sizes, int n_in,
                              void* d_out, int out_size, void* d_ws, size_t ws_size,
                              hipStream_t stream) {
  const float* x    = (const float*)d_in[0];
  const float* WihF = (const float*)d_in[1];
  const float* WhhF = (const float*)d_in[2];
  const float* bihF = (const float*)d_in[3];
  const float* bhhF = (const float*)d_in[4];
  const float* WihB = (const float*)d_in[5];
  const float* WhhB = (const float*)d_in[6];
  const float* bihB = (const float*)d_in[7];
  const float* bhhB = (const float*)d_in[8];

  // ws layout: hbuf (2 dirs * 2 bufs * 32 * 512 bf16 = 131072 B) + bars (512 B)
  unsigned short* hbuf = (unsigned short*)d_ws;
  unsigned* bars       = (unsigned*)((char*)d_ws + (size_t)2 * 2 * TB * TN * 2);

  prep_kernel<<<64, 256, 0, stream>>>((short4v*)hbuf, bars);

  gru_kernel<<<32, 256, 0, stream>>>(
      x, WihF, WhhF, WihB, WhhB,
      bihF, bhhF, bihB, bhhB,
      hbuf, bars, (float*)d_out);
}

// Round 4
// 9186.106 us; speedup vs baseline: 1.3026x; 1.0086x over previous
//
#include <hip/hip_runtime.h>
#include <hip/hip_bf16.h>
#include <stdint.h>

#define TB 32      // batch
#define TT 1024    // time steps
#define TN 512     // hidden

typedef __attribute__((ext_vector_type(8))) short short8;
typedef __attribute__((ext_vector_type(4))) float f32x4;
typedef __attribute__((ext_vector_type(4))) short short4v;

static __device__ inline unsigned short f2bf(float f) {
  union { __hip_bfloat16 h; unsigned short u; } c;
  c.h = __float2bfloat16(f);
  return c.u;
}

static __device__ inline short8 pack_bf8(const float* __restrict__ p) {
  float4 a = *(const float4*)p;
  float4 b = *(const float4*)(p + 4);
  short8 o;
  o[0] = (short)f2bf(a.x); o[1] = (short)f2bf(a.y);
  o[2] = (short)f2bf(a.z); o[3] = (short)f2bf(a.w);
  o[4] = (short)f2bf(b.x); o[5] = (short)f2bf(b.y);
  o[6] = (short)f2bf(b.z); o[7] = (short)f2bf(b.w);
  return o;
}

// ---------------- prep: zero h ping-pong buffers & flag words (ws is 0xAA-poisoned) ----
__global__ void prep_kernel(short4v* __restrict__ hbuf, unsigned* __restrict__ flags) {
  const int i = blockIdx.x * 256 + threadIdx.x;
  if (i < (2 * 2 * TB * TN / 4)) {  // 16384 short4v
    short4v z; z.x = 0; z.y = 0; z.z = 0; z.w = 0;
    hbuf[i] = z;
  }
  if (i < 128) flags[i] = 0u;
}

// ---------------- persistent bidirectional GRU recurrence ----------------
// grid: 32 blocks (dir = blk>>4, slice j = blk&15), 256 threads (4 waves).
// wave w: mt = w&1 (batch rows mt*16..+15), nt = w>>1 (cols nt*16..+15 of slice).
// The (dir, mt) groups are fully independent recurrences (batch rows don't mix).
// Sync: per-producer monotone flag words (value = t+1) + ballot-poll on the
// consumer side — NO same-address atomic RMW (round-3's serialized fetch_add
// at the coherence point was the ~9 us/step pole), NO agent fences (round-2's
// buffer_wbl2/inv L2 walks).
__global__ __launch_bounds__(256, 1) void gru_kernel(
    const float* __restrict__ x,            // [B][T][N] fp32
    const float* __restrict__ wihF, const float* __restrict__ whhF,
    const float* __restrict__ wihB, const float* __restrict__ whhB,
    const float* __restrict__ bihF, const float* __restrict__ bhhF,
    const float* __restrict__ bihB, const float* __restrict__ bhhB,
    unsigned short* __restrict__ hbuf,      // [2 dirs][2 bufs][B][N] bf16
    unsigned* __restrict__ flags,           // [2 dirs][2 mt][32 producers] u32
    float* __restrict__ out)                // [B][T][2N] fp32
{
  const int wg   = blockIdx.x;
  const int dir  = wg >> 4;
  const int j    = wg & 15;
  const int tid  = threadIdx.x;
  const int lane = tid & 63;
  const int w    = tid >> 6;
  const int mt   = w & 1;
  const int nt   = w >> 1;
  const int l15  = lane & 15;
  const int l4   = lane >> 4;                 // 0..3
  const int coln = j * 32 + nt * 16 + l15;    // global hidden col 0..511
  const int brow = mt * 16 + l15;             // batch row for A-frags

  const float* wih = dir ? wihB : wihF;
  const float* whh = dir ? whhB : whhF;
  const float* bih = dir ? bihB : bihF;
  const float* bhh = dir ? bhhB : bhhF;
  unsigned short* hb = hbuf + dir * (2 * TB * TN);
  unsigned* flg = flags + (dir * 2 + mt) * 32;  // this group's 32 flag words (128 B)
  const int prod = j * 2 + nt;                  // this wave's producer slot

  // Wih r,z gate fragments in LDS, fragment-ordered (conflict-free ds_read_b128). 64KB.
  __shared__ unsigned short wih_lds[2][2][16][512];

  // ---- one-time: convert weights fp32 -> bf16 fragments ----
  short8 bwhh[3][16];
#pragma unroll
  for (int g = 0; g < 3; ++g)
#pragma unroll
    for (int ks = 0; ks < 16; ++ks)
      bwhh[g][ks] = pack_bf8(whh + (size_t)(g * TN + coln) * TN + ks * 32 + l4 * 8);

  short8 bwih_n[16];
#pragma unroll
  for (int ks = 0; ks < 16; ++ks)
    bwih_n[ks] = pack_bf8(wih + (size_t)(2 * TN + coln) * TN + ks * 32 + l4 * 8);

  if (mt == 0) {
#pragma unroll
    for (int g = 0; g < 2; ++g)
#pragma unroll
      for (int ks = 0; ks < 16; ++ks) {
        short8 f = pack_bf8(wih + (size_t)(g * TN + coln) * TN + ks * 32 + l4 * 8);
        *(short8*)&wih_lds[nt][g][ks][lane * 8] = f;
      }
  }

  const float bias_r  = bih[coln] + bhh[coln];
  const float bias_z  = bih[TN + coln] + bhh[TN + coln];
  const float bias_in = bih[2 * TN + coln];
  const float bias_hn = bhh[2 * TN + coln];

  // fp32 recurrent state for this wave's own 4 (row,col) patch entries.
  float hstate[4] = {0.f, 0.f, 0.f, 0.f};
  int dead = 0;  // set if a wait ever times out (prevents container-killing hang)

  __syncthreads();  // wih_lds ready

  const int bpat = mt * 16 + l4 * 4;

  for (int t = 0; t < TT; ++t) {
    const int st = dir ? (TT - 1 - t) : t;   // source time index into x

    f32x4 acc_r  = {bias_r,  bias_r,  bias_r,  bias_r};
    f32x4 acc_z  = {bias_z,  bias_z,  bias_z,  bias_z};
    f32x4 acc_in = {bias_in, bias_in, bias_in, bias_in};
    f32x4 acc_hn = {bias_hn, bias_hn, bias_hn, bias_hn};

    // ---- gi = x_t @ Wih^T (barrier-independent: overlaps the wait) ----
    const float* xr = x + (size_t)brow * (TT * TN) + (size_t)st * TN + l4 * 8;
    short8 af[16];
#pragma unroll
    for (int ks = 0; ks < 16; ++ks) af[ks] = pack_bf8(xr + ks * 32);
#pragma unroll
    for (int ks = 0; ks < 16; ++ks) {
      short8 b0 = *(const short8*)&wih_lds[nt][0][ks][lane * 8];
      acc_r = __builtin_amdgcn_mfma_f32_16x16x32_bf16(af[ks], b0, acc_r, 0, 0, 0);
      short8 b1 = *(const short8*)&wih_lds[nt][1][ks][lane * 8];
      acc_z = __builtin_amdgcn_mfma_f32_16x16x32_bf16(af[ks], b1, acc_z, 0, 0, 0);
      acc_in = __builtin_amdgcn_mfma_f32_16x16x32_bf16(af[ks], bwih_n[ks], acc_in, 0, 0, 0);
    }

    // x patch for the output epilogue (fp32, barrier-independent)
    float xv[4];
#pragma unroll
    for (int r = 0; r < 4; ++r)
      xv[r] = x[(size_t)(bpat + r) * (TT * TN) + (size_t)st * TN + coln];

    // ---- wait: all 32 same-(dir,mt) producers published step t-1 (flag >= t) ----
    if (t > 0 && !dead) {
      const unsigned target = (unsigned)t;
      int spins = 0;
      for (;;) {
        unsigned v = __hip_atomic_load(&flg[lane & 31], __ATOMIC_RELAXED,
                                       __HIP_MEMORY_SCOPE_AGENT);
        if (__ballot(v >= target) == ~0ull) break;
        if (++spins > (1 << 22)) { dead = 1; break; }
      }
      asm volatile("" ::: "memory");  // keep h loads below the poll
    }

    // ---- gh = h_{t-1} @ Whh^T  (coherent 8B loads: bypass stale caches) ----
    const unsigned short* hr = hb + ((t + 1) & 1) * (TB * TN) + (size_t)brow * TN + l4 * 8;
#pragma unroll
    for (int ks = 0; ks < 16; ++ks) {
      union { unsigned long long u[2]; short8 s; } cvt;
      cvt.u[0] = __hip_atomic_load((const unsigned long long*)(hr + ks * 32),
                                   __ATOMIC_RELAXED, __HIP_MEMORY_SCOPE_AGENT);
      cvt.u[1] = __hip_atomic_load((const unsigned long long*)(hr + ks * 32 + 4),
                                   __ATOMIC_RELAXED, __HIP_MEMORY_SCOPE_AGENT);
      af[ks] = cvt.s;
    }
#pragma unroll
    for (int ks = 0; ks < 16; ++ks) {
      acc_r  = __builtin_amdgcn_mfma_f32_16x16x32_bf16(af[ks], bwhh[0][ks], acc_r, 0, 0, 0);
      acc_z  = __builtin_amdgcn_mfma_f32_16x16x32_bf16(af[ks], bwhh[1][ks], acc_z, 0, 0, 0);
      acc_hn = __builtin_amdgcn_mfma_f32_16x16x32_bf16(af[ks], bwhh[2][ks], acc_hn, 0, 0, 0);
    }

    // ---- gates + state update; publish h ASAP (coherent packed 4B stores) ----
    unsigned short* hw = hb + (t & 1) * (TB * TN);
    float hout[4];
#pragma unroll
    for (int r = 0; r < 4; ++r) {
      float rg = 1.0f / (1.0f + __expf(-acc_r[r]));
      float zg = 1.0f / (1.0f + __expf(-acc_z[r]));
      float e2 = __expf(2.0f * (acc_in[r] + rg * acc_hn[r]));
      float ng = 1.0f - 2.0f / (e2 + 1.0f);
      float hnew = (1.0f - zg) * ng + zg * hstate[r];
      hstate[r] = hnew;
      hout[r] = hnew;
      // pack (col, col+1) from the even/odd lane pair into one 4B coherent store
      unsigned short us = f2bf(hnew);
      int other = __shfl_xor((int)us, 1, 64);
      if ((lane & 1) == 0) {
        unsigned val = (unsigned)us | ((unsigned)(other & 0xFFFF) << 16);
        __hip_atomic_store((unsigned*)(hw + (size_t)(bpat + r) * TN + coln), val,
                           __ATOMIC_RELAXED, __HIP_MEMORY_SCOPE_AGENT);
      }
    }

    // ---- publish step t: drain h stores (and h loads), then set our flag word ----
    asm volatile("s_waitcnt vmcnt(0)" ::: "memory");
    if (lane == 0)
      __hip_atomic_store(&flg[prod], (unsigned)(t + 1), __ATOMIC_RELAXED,
                         __HIP_MEMORY_SCOPE_AGENT);

    // ---- out stores AFTER the publish (drain during next step's overlap window) ----
#pragma unroll
    for (int r = 0; r < 4; ++r) {
      __builtin_nontemporal_store(hout[r] + xv[r],
          out + (size_t)(bpat + r) * (TT * 2 * TN) + (size_t)t * (2 * TN) + dir * TN + coln);
    }
  }
}

// ---------------- launch ----------------
extern "C" void kernel_launch(void* const* d_in, const int* in_sizes, int n_in,
                              void* d_out, int out_size, void* d_ws, size_t ws_size,
                              hipStream_t stream) {
  const float* x    = (const float*)d_in[0];
  const float* WihF = (const float*)d_in[1];
  const float* WhhF = (const float*)d_in[2];
  const float* bihF = (const float*)d_in[3];
  const float* bhhF = (const float*)d_in[4];
  const float* WihB = (const float*)d_in[5];
  const float* WhhB = (const float*)d_in[6];
  const float* bihB = (const float*)d_in[7];
  const float* bhhB = (const float*)d_in[8];

  // ws layout: hbuf (2 dirs * 2 bufs * 32 * 512 bf16 = 131072 B) + flags (512 B)
  unsigned short* hbuf = (unsigned short*)d_ws;
  unsigned* flags      = (unsigned*)((char*)d_ws + (size_t)2 * 2 * TB * TN * 2);

  prep_kernel<<<64, 256, 0, stream>>>((short4v*)hbuf, flags);

  gru_kernel<<<32, 256, 0, stream>>>(
      x, WihF, WhhF, WihB, WhhB,
      bihF, bhhF, bihB, bhhB,
      hbuf, flags, (float*)d_out);
}